// Round 1
// baseline (5661.584 us; speedup 1.0000x reference)
//
#include <hip/hip_runtime.h>

#define NN 50000
#define NE 800000
#define LN_EPS 1e-5f

// ---------------------------------------------------------------------------
// GEMM: Y[NN,256] = X[NN,K] @ W[K,256] (+ optional bias), f32.
// Block: 256 threads -> 16 rows x 256 cols tile. Thread (tr,tc): tr=t>>6 owns
// 4 rows, tc=t&63 owns 4 cols. Per k: 2 x ds_read_b128 + 16 FMA (VALU-bound).
// ---------------------------------------------------------------------------
template <int K>
__global__ __launch_bounds__(256) void gemm_k(const float* __restrict__ X,
                                              const float* __restrict__ W,
                                              const float* __restrict__ bias,
                                              float* __restrict__ Y) {
    __shared__ float ws[32][256];   // [k][col]
    __shared__ float xs[32][16];    // [k][row]  (transposed)
    const int t = threadIdx.x;
    const int tc = t & 63;
    const int tr = t >> 6;
    const int row0 = blockIdx.x * 16;

    float acc[4][4];
#pragma unroll
    for (int i = 0; i < 4; ++i)
#pragma unroll
        for (int j = 0; j < 4; ++j) acc[i][j] = 0.f;

    for (int k0 = 0; k0 < K; k0 += 32) {
        __syncthreads();
#pragma unroll
        for (int i = 0; i < 32; ++i) ws[i][t] = W[(size_t)(k0 + i) * 256 + t];
        {
            const int f = t * 2;
            const int r = f >> 5;
            const int k = f & 31;
            xs[k][r]     = X[(size_t)(row0 + r) * K + k0 + k];
            xs[k + 1][r] = X[(size_t)(row0 + r) * K + k0 + k + 1];
        }
        __syncthreads();
#pragma unroll
        for (int k = 0; k < 32; ++k) {
            const float4 wv = *(const float4*)(&ws[k][tc * 4]);
            const float4 xv = *(const float4*)(&xs[k][tr * 4]);
            const float xa[4] = {xv.x, xv.y, xv.z, xv.w};
            const float wa[4] = {wv.x, wv.y, wv.z, wv.w};
#pragma unroll
            for (int i = 0; i < 4; ++i)
#pragma unroll
                for (int j = 0; j < 4; ++j)
                    acc[i][j] = fmaf(xa[i], wa[j], acc[i][j]);
        }
    }

    float4 bv;
    if (bias) {
        bv = ((const float4*)bias)[tc];
    } else {
        bv.x = bv.y = bv.z = bv.w = 0.f;
    }
#pragma unroll
    for (int i = 0; i < 4; ++i) {
        float4 o;
        o.x = acc[i][0] + bv.x;
        o.y = acc[i][1] + bv.y;
        o.z = acc[i][2] + bv.z;
        o.w = acc[i][3] + bv.w;
        ((float4*)(Y + (size_t)(row0 + tr * 4 + i) * 256))[tc] = o;
    }
}

// ---------------------------------------------------------------------------
// degree: deg[col[e]] += 1  (f32 atomics, exact for counts < 2^24)
// ---------------------------------------------------------------------------
__global__ __launch_bounds__(256) void deg_k(const int* __restrict__ col,
                                             float* __restrict__ deg) {
    const int e = blockIdx.x * 256 + threadIdx.x;
    if (e < NE) atomicAdd(&deg[col[e]], 1.0f);
}

__global__ __launch_bounds__(256) void dinv_k(float* __restrict__ d) {
    const int i = blockIdx.x * 256 + threadIdx.x;
    if (i < NN) d[i] = rsqrtf(d[i] + 1.0f);
}

// ---------------------------------------------------------------------------
// scatter: agg[col] += H[row] * dinv[row]*dinv[col].  One wave per edge;
// lane l owns channels 4l..4l+3 (coalesced 1KB gather, 4 atomic f32 adds).
// ---------------------------------------------------------------------------
__global__ __launch_bounds__(256) void scatter_k(const float* __restrict__ H,
                                                 const int* __restrict__ row,
                                                 const int* __restrict__ col,
                                                 const float* __restrict__ dinv,
                                                 float* __restrict__ agg) {
    const int gid = blockIdx.x * 256 + threadIdx.x;
    const int e = gid >> 6;
    const int lane = threadIdx.x & 63;
    if (e >= NE) return;
    const int r = row[e];
    const int c = col[e];
    const float w = dinv[r] * dinv[c];
    const float4 v = ((const float4*)(H + (size_t)r * 256))[lane];
    float* dst = agg + (size_t)c * 256 + (size_t)lane * 4;
    atomicAdd(dst + 0, v.x * w);
    atomicAdd(dst + 1, v.y * w);
    atomicAdd(dst + 2, v.z * w);
    atomicAdd(dst + 3, v.w * w);
}

// ---------------------------------------------------------------------------
// post: t = agg + H*dinv^2 + bias ; LayerNorm(t) ; (+resid) ; ReLU ; store.
// One wave per node, lane l owns channels 4l..4l+3; shfl_xor reductions.
// ---------------------------------------------------------------------------
__global__ __launch_bounds__(256) void post_k(const float* __restrict__ agg,
                                              const float* __restrict__ H,
                                              const float* __restrict__ dinv,
                                              const float* __restrict__ bias,
                                              const float* __restrict__ gamma,
                                              const float* __restrict__ beta,
                                              const float* __restrict__ resid,
                                              float* __restrict__ out) {
    const int node = blockIdx.x * 4 + (threadIdx.x >> 6);
    const int lane = threadIdx.x & 63;
    if (node >= NN) return;
    const float di = dinv[node];
    const float d2 = di * di;

    const float4 a = ((const float4*)(agg + (size_t)node * 256))[lane];
    const float4 h = ((const float4*)(H + (size_t)node * 256))[lane];
    const float4 b = ((const float4*)bias)[lane];

    float4 t;
    t.x = a.x + h.x * d2 + b.x;
    t.y = a.y + h.y * d2 + b.y;
    t.z = a.z + h.z * d2 + b.z;
    t.w = a.w + h.w * d2 + b.w;

    float s = t.x + t.y + t.z + t.w;
    float q = t.x * t.x + t.y * t.y + t.z * t.z + t.w * t.w;
#pragma unroll
    for (int off = 1; off < 64; off <<= 1) {
        s += __shfl_xor(s, off, 64);
        q += __shfl_xor(q, off, 64);
    }
    const float mu = s * (1.f / 256.f);
    const float var = q * (1.f / 256.f) - mu * mu;
    const float rs = rsqrtf(var + LN_EPS);

    const float4 g = ((const float4*)gamma)[lane];
    const float4 be = ((const float4*)beta)[lane];
    t.x = (t.x - mu) * rs * g.x + be.x;
    t.y = (t.y - mu) * rs * g.y + be.y;
    t.z = (t.z - mu) * rs * g.z + be.z;
    t.w = (t.w - mu) * rs * g.w + be.w;

    if (resid) {
        const float4 rv = ((const float4*)(resid + (size_t)node * 256))[lane];
        t.x += rv.x;
        t.y += rv.y;
        t.z += rv.z;
        t.w += rv.w;
    }
    t.x = fmaxf(t.x, 0.f);
    t.y = fmaxf(t.y, 0.f);
    t.z = fmaxf(t.z, 0.f);
    t.w = fmaxf(t.w, 0.f);

    ((float4*)(out + (size_t)node * 256))[lane] = t;
}

// ---------------------------------------------------------------------------
extern "C" void kernel_launch(void* const* d_in, const int* in_sizes, int n_in,
                              void* d_out, int out_size, void* d_ws, size_t ws_size,
                              hipStream_t stream) {
    const float* x    = (const float*)d_in[0];
    const int*   eidx = (const int*)d_in[1];
    const float* W1   = (const float*)d_in[2];
    const float* b1   = (const float*)d_in[3];
    const float* W2   = (const float*)d_in[4];
    const float* b2   = (const float*)d_in[5];
    const float* ln1g = (const float*)d_in[6];
    const float* ln1b = (const float*)d_in[7];
    const float* ln2g = (const float*)d_in[8];
    const float* ln2b = (const float*)d_in[9];
    const float* pW   = (const float*)d_in[10];
    const float* pb   = (const float*)d_in[11];

    const int* row = eidx;        // edge_index[0]
    const int* col = eidx + NE;   // edge_index[1]
    float* out = (float*)d_out;

    float* A    = (float*)d_ws;               // [NN,256]  51.2 MB
    float* B    = A + (size_t)NN * 256;       // [NN,256]  51.2 MB
    float* dinv = B + (size_t)NN * 256;       // [NN]       0.2 MB

    // degree -> dinv
    hipMemsetAsync(dinv, 0, NN * sizeof(float), stream);
    deg_k<<<(NE + 255) / 256, 256, 0, stream>>>(col, dinv);
    dinv_k<<<(NN + 255) / 256, 256, 0, stream>>>(dinv);

    // ---- layer 1: h = relu(LN(gcn_conv(x, W1, b1))) -> B
    gemm_k<128><<<NN / 16, 256, 0, stream>>>(x, W1, nullptr, A);      // A = x@W1
    hipMemsetAsync(B, 0, (size_t)NN * 256 * sizeof(float), stream);
    scatter_k<<<(NE * 64) / 256, 256, 0, stream>>>(A, row, col, dinv, B);
    post_k<<<NN / 4, 256, 0, stream>>>(B, A, dinv, b1, ln1g, ln1b, nullptr, B);

    // ---- identity = x @ proj_W + proj_b -> d_out
    gemm_k<128><<<NN / 16, 256, 0, stream>>>(x, pW, pb, out);

    // ---- layer 2: out = relu(LN(gcn_conv(h, W2, b2)) + identity)
    gemm_k<256><<<NN / 16, 256, 0, stream>>>(B, W2, nullptr, A);      // A = h@W2
    hipMemsetAsync(B, 0, (size_t)NN * 256 * sizeof(float), stream);
    scatter_k<<<(NE * 64) / 256, 256, 0, stream>>>(A, row, col, dinv, B);
    post_k<<<NN / 4, 256, 0, stream>>>(B, A, dinv, b2, ln2g, ln2b, out, out);
}

// Round 2
// 644.620 us; speedup vs baseline: 8.7828x; 8.7828x over previous
//
#include <hip/hip_runtime.h>

#define NN 50000
#define NE 800000
#define LN_EPS 1e-5f

// ---------------------------------------------------------------------------
// GEMM: Y[NN,256] = X[NN,K] @ W[K,256] (+ optional bias), f32.
// Block: 256 threads -> 16 rows x 256 cols tile; 4x4 register tile per thread.
// ---------------------------------------------------------------------------
template <int K>
__global__ __launch_bounds__(256) void gemm_k(const float* __restrict__ X,
                                              const float* __restrict__ W,
                                              const float* __restrict__ bias,
                                              float* __restrict__ Y) {
    __shared__ float ws[32][256];   // [k][col]
    __shared__ float xs[32][16];    // [k][row]  (transposed)
    const int t = threadIdx.x;
    const int tc = t & 63;
    const int tr = t >> 6;
    const int row0 = blockIdx.x * 16;

    float acc[4][4];
#pragma unroll
    for (int i = 0; i < 4; ++i)
#pragma unroll
        for (int j = 0; j < 4; ++j) acc[i][j] = 0.f;

    for (int k0 = 0; k0 < K; k0 += 32) {
        __syncthreads();
#pragma unroll
        for (int i = 0; i < 32; ++i) ws[i][t] = W[(size_t)(k0 + i) * 256 + t];
        {
            const int f = t * 2;
            const int r = f >> 5;
            const int k = f & 31;
            xs[k][r]     = X[(size_t)(row0 + r) * K + k0 + k];
            xs[k + 1][r] = X[(size_t)(row0 + r) * K + k0 + k + 1];
        }
        __syncthreads();
#pragma unroll
        for (int k = 0; k < 32; ++k) {
            const float4 wv = *(const float4*)(&ws[k][tc * 4]);
            const float4 xv = *(const float4*)(&xs[k][tr * 4]);
            const float xa[4] = {xv.x, xv.y, xv.z, xv.w};
            const float wa[4] = {wv.x, wv.y, wv.z, wv.w};
#pragma unroll
            for (int i = 0; i < 4; ++i)
#pragma unroll
                for (int j = 0; j < 4; ++j)
                    acc[i][j] = fmaf(xa[i], wa[j], acc[i][j]);
        }
    }

    float4 bv;
    if (bias) {
        bv = ((const float4*)bias)[tc];
    } else {
        bv.x = bv.y = bv.z = bv.w = 0.f;
    }
#pragma unroll
    for (int i = 0; i < 4; ++i) {
        float4 o;
        o.x = acc[i][0] + bv.x;
        o.y = acc[i][1] + bv.y;
        o.z = acc[i][2] + bv.z;
        o.w = acc[i][3] + bv.w;
        ((float4*)(Y + (size_t)(row0 + tr * 4 + i) * 256))[tc] = o;
    }
}

// ---------------------------------------------------------------------------
// CSR build: count -> scan -> dinv -> fill
// ---------------------------------------------------------------------------
__global__ __launch_bounds__(256) void count_k(const int* __restrict__ col,
                                               int* __restrict__ rowptr) {
    const int e = blockIdx.x * 256 + threadIdx.x;
    if (e < NE) atomicAdd(&rowptr[col[e] + 1], 1);
}

// single-block inclusive scan over n ints (n = NN+1)
__global__ __launch_bounds__(1024) void scan_k(int* __restrict__ p, int n) {
    __shared__ int tmp[1024];
    int carry = 0;
    for (int base = 0; base < n; base += 1024) {
        const int i = base + threadIdx.x;
        tmp[threadIdx.x] = (i < n) ? p[i] : 0;
        __syncthreads();
#pragma unroll
        for (int off = 1; off < 1024; off <<= 1) {
            const int t = (threadIdx.x >= off) ? tmp[threadIdx.x - off] : 0;
            __syncthreads();
            tmp[threadIdx.x] += t;
            __syncthreads();
        }
        if (i < n) p[i] = tmp[threadIdx.x] + carry;
        carry += tmp[1023];
        __syncthreads();
    }
}

// dinv[i] = rsqrt(deg_i + 1), deg from rowptr (before fill destroys it)
__global__ __launch_bounds__(256) void dinv_k(const int* __restrict__ rowptr,
                                              float* __restrict__ dinv) {
    const int i = blockIdx.x * 256 + threadIdx.x;
    if (i < NN) dinv[i] = rsqrtf((float)(rowptr[i + 1] - rowptr[i]) + 1.0f);
}

// fill: srcs[pos] = row[e], bucketed by col[e]. Destroys rowptr -> endptr.
__global__ __launch_bounds__(256) void fill_k(const int* __restrict__ row,
                                              const int* __restrict__ col,
                                              int* __restrict__ rowptr,
                                              int* __restrict__ srcs) {
    const int e = blockIdx.x * 256 + threadIdx.x;
    if (e >= NE) return;
    const int pos = atomicAdd(&rowptr[col[e]], 1);
    srcs[pos] = row[e];
}

// ---------------------------------------------------------------------------
// Fused gather + self-loop + bias + LayerNorm (+resid) + ReLU.
// One wave per destination node; lane owns channels 4l..4l+3.
// agg_total = dc * (sum_r h[r]*dinv[r] + h[c]*dc)
// endptr[i] = end of node i's bucket; start = endptr[i-1] (0 for i==0).
// ---------------------------------------------------------------------------
__global__ __launch_bounds__(256) void gather_post_k(
    const float* __restrict__ H, const int* __restrict__ endptr,
    const int* __restrict__ srcs, const float* __restrict__ dinv,
    const float* __restrict__ bias, const float* __restrict__ gamma,
    const float* __restrict__ beta, const float* __restrict__ resid,
    float* __restrict__ out) {
    const int node = blockIdx.x * 4 + (threadIdx.x >> 6);
    const int lane = threadIdx.x & 63;
    if (node >= NN) return;
    const int start = node ? endptr[node - 1] : 0;
    const int end = endptr[node];

    float4 acc = {0.f, 0.f, 0.f, 0.f};
    int j = start;
    for (; j + 1 < end; j += 2) {
        const int r0 = srcs[j];
        const int r1 = srcs[j + 1];
        const float w0 = dinv[r0];
        const float w1 = dinv[r1];
        const float4 v0 = ((const float4*)(H + (size_t)r0 * 256))[lane];
        const float4 v1 = ((const float4*)(H + (size_t)r1 * 256))[lane];
        acc.x += v0.x * w0 + v1.x * w1;
        acc.y += v0.y * w0 + v1.y * w1;
        acc.z += v0.z * w0 + v1.z * w1;
        acc.w += v0.w * w0 + v1.w * w1;
    }
    if (j < end) {
        const int r0 = srcs[j];
        const float w0 = dinv[r0];
        const float4 v0 = ((const float4*)(H + (size_t)r0 * 256))[lane];
        acc.x += v0.x * w0;
        acc.y += v0.y * w0;
        acc.z += v0.z * w0;
        acc.w += v0.w * w0;
    }

    const float dc = dinv[node];
    const float4 h = ((const float4*)(H + (size_t)node * 256))[lane];
    const float4 b = ((const float4*)bias)[lane];
    float4 t;
    t.x = (acc.x + h.x * dc) * dc + b.x;
    t.y = (acc.y + h.y * dc) * dc + b.y;
    t.z = (acc.z + h.z * dc) * dc + b.z;
    t.w = (acc.w + h.w * dc) * dc + b.w;

    float s = t.x + t.y + t.z + t.w;
    float q = t.x * t.x + t.y * t.y + t.z * t.z + t.w * t.w;
#pragma unroll
    for (int off = 1; off < 64; off <<= 1) {
        s += __shfl_xor(s, off, 64);
        q += __shfl_xor(q, off, 64);
    }
    const float mu = s * (1.f / 256.f);
    const float var = q * (1.f / 256.f) - mu * mu;
    const float rs = rsqrtf(var + LN_EPS);

    const float4 g = ((const float4*)gamma)[lane];
    const float4 be = ((const float4*)beta)[lane];
    t.x = (t.x - mu) * rs * g.x + be.x;
    t.y = (t.y - mu) * rs * g.y + be.y;
    t.z = (t.z - mu) * rs * g.z + be.z;
    t.w = (t.w - mu) * rs * g.w + be.w;

    if (resid) {
        const float4 rv = ((const float4*)(resid + (size_t)node * 256))[lane];
        t.x += rv.x;
        t.y += rv.y;
        t.z += rv.z;
        t.w += rv.w;
    }
    t.x = fmaxf(t.x, 0.f);
    t.y = fmaxf(t.y, 0.f);
    t.z = fmaxf(t.z, 0.f);
    t.w = fmaxf(t.w, 0.f);

    ((float4*)(out + (size_t)node * 256))[lane] = t;
}

// ---------------------------------------------------------------------------
extern "C" void kernel_launch(void* const* d_in, const int* in_sizes, int n_in,
                              void* d_out, int out_size, void* d_ws, size_t ws_size,
                              hipStream_t stream) {
    const float* x    = (const float*)d_in[0];
    const int*   eidx = (const int*)d_in[1];
    const float* W1   = (const float*)d_in[2];
    const float* b1   = (const float*)d_in[3];
    const float* W2   = (const float*)d_in[4];
    const float* b2   = (const float*)d_in[5];
    const float* ln1g = (const float*)d_in[6];
    const float* ln1b = (const float*)d_in[7];
    const float* ln2g = (const float*)d_in[8];
    const float* ln2b = (const float*)d_in[9];
    const float* pW   = (const float*)d_in[10];
    const float* pb   = (const float*)d_in[11];

    const int* row = eidx;        // edge_index[0]
    const int* col = eidx + NE;   // edge_index[1]
    float* out = (float*)d_out;

    float* A      = (float*)d_ws;                 // [NN,256]  51.2 MB
    float* B      = A + (size_t)NN * 256;         // [NN,256]  51.2 MB
    float* dinv   = B + (size_t)NN * 256;         // [NN]
    int*   rowptr = (int*)(dinv + NN);            // [NN+1]
    int*   srcs   = rowptr + (NN + 1);            // [NE]

    // ---- CSR build (by destination) + dinv
    hipMemsetAsync(rowptr, 0, (NN + 1) * sizeof(int), stream);
    count_k<<<(NE + 255) / 256, 256, 0, stream>>>(col, rowptr);
    scan_k<<<1, 1024, 0, stream>>>(rowptr, NN + 1);
    dinv_k<<<(NN + 255) / 256, 256, 0, stream>>>(rowptr, dinv);
    fill_k<<<(NE + 255) / 256, 256, 0, stream>>>(row, col, rowptr, srcs);
    // rowptr is now endptr

    // ---- layer 1: B = relu(LN(gcn_conv(x, W1, b1)))
    gemm_k<128><<<NN / 16, 256, 0, stream>>>(x, W1, nullptr, A);   // A = x@W1
    gather_post_k<<<(NN + 3) / 4, 256, 0, stream>>>(A, rowptr, srcs, dinv, b1,
                                                    ln1g, ln1b, nullptr, B);

    // ---- identity = x @ proj_W + proj_b -> d_out
    gemm_k<128><<<NN / 16, 256, 0, stream>>>(x, pW, pb, out);

    // ---- layer 2: out = relu(LN(gcn_conv(h, W2, b2)) + identity)
    gemm_k<256><<<NN / 16, 256, 0, stream>>>(B, W2, nullptr, A);   // A = h@W2
    gather_post_k<<<(NN + 3) / 4, 256, 0, stream>>>(A, rowptr, srcs, dinv, b2,
                                                    ln2g, ln2b, out, out);
}

// Round 3
// 331.897 us; speedup vs baseline: 17.0582x; 1.9422x over previous
//
#include <hip/hip_runtime.h>

#define NN 50000
#define NE 800000
#define LN_EPS 1e-5f

using bf16x8 = __attribute__((ext_vector_type(8))) short;  // 8 bf16 (4 VGPRs)
using f32x4  = __attribute__((ext_vector_type(4))) float;  // MFMA C/D

__device__ __forceinline__ float b2f(unsigned short u) {
    union { unsigned int i; float f; } c;
    c.i = ((unsigned int)u) << 16;
    return c.f;
}
__device__ __forceinline__ unsigned short f2b(float f) {  // RNE
    union { float f; unsigned int i; } c;
    c.f = f;
    const unsigned int i = c.i;
    return (unsigned short)((i + 0x7FFFu + ((i >> 16) & 1u)) >> 16);
}

// ---------------------------------------------------------------------------
// f32 -> bf16 bulk convert (4 elems/thread)
// ---------------------------------------------------------------------------
__global__ __launch_bounds__(256) void cvt_k(const float* __restrict__ X,
                                             short* __restrict__ Xb, int n4) {
    const int i = blockIdx.x * 256 + threadIdx.x;
    if (i >= n4) return;
    const float4 v = ((const float4*)X)[i];
    ushort4 o;
    o.x = f2b(v.x); o.y = f2b(v.y); o.z = f2b(v.z); o.w = f2b(v.w);
    ((ushort4*)Xb)[i] = o;
}

// ---------------------------------------------------------------------------
// Pack W[K][256] f32 -> bf16 MFMA B-fragment order:
// Wp[(((nt*KB)+kb)*64 + lane)*8 + j] = W[32*kb + 8*(lane>>4) + j][16*nt + (lane&15)]
// ---------------------------------------------------------------------------
template <int K>
__global__ __launch_bounds__(256) void pack_w_k(const float* __restrict__ W,
                                                short* __restrict__ Wp) {
    constexpr int KB = K / 32;
    const int i = blockIdx.x * 256 + threadIdx.x;  // grid = K blocks -> K*256 elems
    const int j = i & 7;
    const int l = (i >> 3) & 63;
    const int t = i >> 9;
    const int kb = t % KB;
    const int nt = t / KB;
    const int k = 32 * kb + 8 * (l >> 4) + j;
    const int n = 16 * nt + (l & 15);
    Wp[i] = (short)f2b(W[(size_t)k * 256 + n]);
}

// ---------------------------------------------------------------------------
// MFMA GEMM: Y[NN,256] = X_bf16[NN,K] @ W (packed) [+ bias].
// 256 thr = 4 waves; wave owns 16 rows; A-frags held in regs; 16 n-tiles.
// C/D mapping (m89-verified): col = lane&15, row = (lane>>4)*4 + reg.
// ---------------------------------------------------------------------------
template <int K, bool OUT_BF16>
__global__ __launch_bounds__(256) void gemm_mfma_k(const short* __restrict__ X,
                                                   const short* __restrict__ Wp,
                                                   const float* __restrict__ bias,
                                                   void* __restrict__ Yv) {
    constexpr int KB = K / 32;
    const int lane = threadIdx.x & 63;
    const int wv = threadIdx.x >> 6;
    const int row0 = blockIdx.x * 64 + wv * 16;
    const int r = row0 + (lane & 15);
    const int rc = (r < NN) ? r : (NN - 1);
    const int kof = 8 * (lane >> 4);

    bf16x8 a[KB];
#pragma unroll
    for (int kb = 0; kb < KB; ++kb)
        a[kb] = *(const bf16x8*)(X + (size_t)rc * K + 32 * kb + kof);

    const int orow0 = row0 + (lane >> 4) * 4;
    const int colbase = lane & 15;

    for (int nt = 0; nt < 16; ++nt) {
        f32x4 acc = {0.f, 0.f, 0.f, 0.f};
#pragma unroll
        for (int kb = 0; kb < KB; ++kb) {
            const bf16x8 b = ((const bf16x8*)Wp)[(nt * KB + kb) * 64 + lane];
            acc = __builtin_amdgcn_mfma_f32_16x16x32_bf16(a[kb], b, acc, 0, 0, 0);
        }
        const int col = nt * 16 + colbase;
        const float bv = bias ? bias[col] : 0.f;
#pragma unroll
        for (int rg = 0; rg < 4; ++rg) {
            const int orow = orow0 + rg;
            if (orow < NN) {
                const float v = acc[rg] + bv;
                if (OUT_BF16)
                    ((short*)Yv)[(size_t)orow * 256 + col] = (short)f2b(v);
                else
                    ((float*)Yv)[(size_t)orow * 256 + col] = v;
            }
        }
    }
}

// ---------------------------------------------------------------------------
// CSR build: count -> hierarchical scan -> dinv -> fill
// ---------------------------------------------------------------------------
__global__ __launch_bounds__(256) void count_k(const int* __restrict__ col,
                                               int* __restrict__ rowptr) {
    const int e = blockIdx.x * 256 + threadIdx.x;
    if (e < NE) atomicAdd(&rowptr[col[e] + 1], 1);
}

__global__ __launch_bounds__(256) void block_sum_k(const int* __restrict__ p,
                                                   int* __restrict__ psum, int n) {
    __shared__ int sh[256];
    const int t = threadIdx.x;
    const int i = blockIdx.x * 256 + t;
    sh[t] = (i < n) ? p[i] : 0;
    __syncthreads();
#pragma unroll
    for (int off = 128; off > 0; off >>= 1) {
        if (t < off) sh[t] += sh[t + off];
        __syncthreads();
    }
    if (t == 0) psum[blockIdx.x] = sh[0];
}

// inclusive scan within block + carry from earlier blocks (nblk <= 256)
__global__ __launch_bounds__(256) void scan_apply_k(int* __restrict__ p,
                                                    const int* __restrict__ psum,
                                                    int n, int nblk) {
    __shared__ int sh[256];
    const int t = threadIdx.x;
    const int b = blockIdx.x;
    const int i = b * 256 + t;
    sh[t] = (t < b && t < nblk) ? psum[t] : 0;
    __syncthreads();
#pragma unroll
    for (int off = 128; off > 0; off >>= 1) {
        if (t < off) sh[t] += sh[t + off];
        __syncthreads();
    }
    const int carry = sh[0];
    __syncthreads();
    sh[t] = (i < n) ? p[i] : 0;
    __syncthreads();
#pragma unroll
    for (int off = 1; off < 256; off <<= 1) {
        const int u = (t >= off) ? sh[t - off] : 0;
        __syncthreads();
        sh[t] += u;
        __syncthreads();
    }
    if (i < n) p[i] = sh[t] + carry;
}

__global__ __launch_bounds__(256) void dinv_k(const int* __restrict__ rowptr,
                                              float* __restrict__ dinv) {
    const int i = blockIdx.x * 256 + threadIdx.x;
    if (i < NN) dinv[i] = rsqrtf((float)(rowptr[i + 1] - rowptr[i]) + 1.0f);
}

__global__ __launch_bounds__(256) void fill_k(const int* __restrict__ row,
                                              const int* __restrict__ col,
                                              int* __restrict__ rowptr,
                                              int* __restrict__ srcs) {
    const int e = blockIdx.x * 256 + threadIdx.x;
    if (e >= NE) return;
    const int pos = atomicAdd(&rowptr[col[e]], 1);
    srcs[pos] = row[e];
}

// ---------------------------------------------------------------------------
// Fused gather + self-loop + bias + LayerNorm (+resid) + ReLU.  H is bf16.
// One wave per dst node; lane owns channels 4l..4l+3 (8B bf16 loads).
// ---------------------------------------------------------------------------
template <bool OUT_BF16>
__global__ __launch_bounds__(256) void gather_post_k(
    const short* __restrict__ H, const int* __restrict__ endptr,
    const int* __restrict__ srcs, const float* __restrict__ dinv,
    const float* __restrict__ bias, const float* __restrict__ gamma,
    const float* __restrict__ beta, const float* __restrict__ resid,
    void* __restrict__ outv) {
    const int node = blockIdx.x * 4 + (threadIdx.x >> 6);
    const int lane = threadIdx.x & 63;
    if (node >= NN) return;
    const int start = node ? endptr[node - 1] : 0;
    const int end = endptr[node];

    float a0 = 0.f, a1 = 0.f, a2 = 0.f, a3 = 0.f;
    int j = start;
    for (; j + 1 < end; j += 2) {
        const int r0 = srcs[j];
        const int r1 = srcs[j + 1];
        const float w0 = dinv[r0];
        const float w1 = dinv[r1];
        const ushort4 v0 = ((const ushort4*)(H + (size_t)r0 * 256))[lane];
        const ushort4 v1 = ((const ushort4*)(H + (size_t)r1 * 256))[lane];
        a0 += b2f(v0.x) * w0 + b2f(v1.x) * w1;
        a1 += b2f(v0.y) * w0 + b2f(v1.y) * w1;
        a2 += b2f(v0.z) * w0 + b2f(v1.z) * w1;
        a3 += b2f(v0.w) * w0 + b2f(v1.w) * w1;
    }
    if (j < end) {
        const int r0 = srcs[j];
        const float w0 = dinv[r0];
        const ushort4 v0 = ((const ushort4*)(H + (size_t)r0 * 256))[lane];
        a0 += b2f(v0.x) * w0;
        a1 += b2f(v0.y) * w0;
        a2 += b2f(v0.z) * w0;
        a3 += b2f(v0.w) * w0;
    }

    const float dc = dinv[node];
    const ushort4 h = ((const ushort4*)(H + (size_t)node * 256))[lane];
    const float4 b = ((const float4*)bias)[lane];
    float t0 = (a0 + b2f(h.x) * dc) * dc + b.x;
    float t1 = (a1 + b2f(h.y) * dc) * dc + b.y;
    float t2 = (a2 + b2f(h.z) * dc) * dc + b.z;
    float t3 = (a3 + b2f(h.w) * dc) * dc + b.w;

    float s = t0 + t1 + t2 + t3;
    float q = t0 * t0 + t1 * t1 + t2 * t2 + t3 * t3;
#pragma unroll
    for (int off = 1; off < 64; off <<= 1) {
        s += __shfl_xor(s, off, 64);
        q += __shfl_xor(q, off, 64);
    }
    const float mu = s * (1.f / 256.f);
    const float var = q * (1.f / 256.f) - mu * mu;
    const float rs = rsqrtf(var + LN_EPS);

    const float4 g = ((const float4*)gamma)[lane];
    const float4 be = ((const float4*)beta)[lane];
    t0 = (t0 - mu) * rs * g.x + be.x;
    t1 = (t1 - mu) * rs * g.y + be.y;
    t2 = (t2 - mu) * rs * g.z + be.z;
    t3 = (t3 - mu) * rs * g.w + be.w;

    if (resid) {
        const float4 rv = ((const float4*)(resid + (size_t)node * 256))[lane];
        t0 += rv.x; t1 += rv.y; t2 += rv.z; t3 += rv.w;
    }
    t0 = fmaxf(t0, 0.f); t1 = fmaxf(t1, 0.f);
    t2 = fmaxf(t2, 0.f); t3 = fmaxf(t3, 0.f);

    if (OUT_BF16) {
        ushort4 o;
        o.x = f2b(t0); o.y = f2b(t1); o.z = f2b(t2); o.w = f2b(t3);
        ((ushort4*)outv)[(size_t)node * 64 + lane] = o;
    } else {
        float4 o;
        o.x = t0; o.y = t1; o.z = t2; o.w = t3;
        ((float4*)outv)[(size_t)node * 64 + lane] = o;
    }
}

// ---------------------------------------------------------------------------
extern "C" void kernel_launch(void* const* d_in, const int* in_sizes, int n_in,
                              void* d_out, int out_size, void* d_ws, size_t ws_size,
                              hipStream_t stream) {
    const float* x    = (const float*)d_in[0];
    const int*   eidx = (const int*)d_in[1];
    const float* W1   = (const float*)d_in[2];
    const float* b1   = (const float*)d_in[3];
    const float* W2   = (const float*)d_in[4];
    const float* b2   = (const float*)d_in[5];
    const float* ln1g = (const float*)d_in[6];
    const float* ln1b = (const float*)d_in[7];
    const float* ln2g = (const float*)d_in[8];
    const float* ln2b = (const float*)d_in[9];
    const float* pW   = (const float*)d_in[10];
    const float* pb   = (const float*)d_in[11];

    const int* row = eidx;        // edge_index[0]
    const int* col = eidx + NE;   // edge_index[1]
    float* out = (float*)d_out;

    short* xb     = (short*)d_ws;                    // [NN,128] bf16 12.8 MB
    short* A      = xb + (size_t)NN * 128;           // [NN,256] bf16 25.6 MB
    short* Bb     = A + (size_t)NN * 256;            // [NN,256] bf16 25.6 MB
    float* dinv   = (float*)(Bb + (size_t)NN * 256); // [NN]
    int*   rowptr = (int*)(dinv + NN);               // [NN+1] (+pad)
    int*   psum   = rowptr + NN + 4;                 // [256]
    int*   srcs   = psum + 256;                      // [NE]
    short* Wp1    = (short*)(srcs + NE);             // 128*256
    short* Wp2    = Wp1 + 128 * 256;                 // 256*256
    short* Wpp    = Wp2 + 256 * 256;                 // 128*256

    const int nscan = NN + 1;
    const int nblk = (nscan + 255) / 256;            // 196

    // ---- preprocessing: convert x, pack weights, CSR build, dinv
    cvt_k<<<(NN * 128 / 4 + 255) / 256, 256, 0, stream>>>(x, xb, NN * 128 / 4);
    pack_w_k<128><<<128, 256, 0, stream>>>(W1, Wp1);
    pack_w_k<256><<<256, 256, 0, stream>>>(W2, Wp2);
    pack_w_k<128><<<128, 256, 0, stream>>>(pW, Wpp);

    hipMemsetAsync(rowptr, 0, (NN + 4) * sizeof(int), stream);
    count_k<<<(NE + 255) / 256, 256, 0, stream>>>(col, rowptr);
    block_sum_k<<<nblk, 256, 0, stream>>>(rowptr, psum, nscan);
    scan_apply_k<<<nblk, 256, 0, stream>>>(rowptr, psum, nscan, nblk);
    dinv_k<<<(NN + 255) / 256, 256, 0, stream>>>(rowptr, dinv);
    fill_k<<<(NE + 255) / 256, 256, 0, stream>>>(row, col, rowptr, srcs);
    // rowptr is now endptr

    // ---- layer 1: Bb = relu(LN(gcn_conv(x, W1, b1)))  [bf16]
    gemm_mfma_k<128, true><<<(NN + 63) / 64, 256, 0, stream>>>(xb, Wp1, nullptr, A);
    gather_post_k<true><<<(NN + 3) / 4, 256, 0, stream>>>(A, rowptr, srcs, dinv,
                                                          b1, ln1g, ln1b, nullptr, Bb);

    // ---- identity = x @ proj_W + proj_b -> d_out (f32)
    gemm_mfma_k<128, false><<<(NN + 63) / 64, 256, 0, stream>>>(xb, Wpp, pb, out);

    // ---- layer 2: out = relu(LN(gcn_conv(h, W2, b2)) + identity)
    gemm_mfma_k<256, true><<<(NN + 63) / 64, 256, 0, stream>>>(Bb, Wp2, nullptr, A);
    gather_post_k<false><<<(NN + 3) / 4, 256, 0, stream>>>(A, rowptr, srcs, dinv,
                                                           b2, ln2g, ln2b, out, out);
}